// Round 6
// baseline (674.017 us; speedup 1.0000x reference)
//
#include <hip/hip_runtime.h>
#include <cstdint>
#include <cstddef>

#define NEG_SLOPE 0.2f

static __device__ __forceinline__ float lrelu(float v) { return v > 0.f ? v : NEG_SLOPE * v; }

// ---------------- CSR build ----------------

__global__ __launch_bounds__(256) void count_deg_k(const int* __restrict__ dst, int E, int N,
                                                   int* __restrict__ cnt) {
    int i = blockIdx.x * 256 + threadIdx.x;
    int base = i * 4;
    if (base + 4 <= E) {
        int4 d4 = *(const int4*)&dst[base];
        if ((unsigned)d4.x < (unsigned)N) atomicAdd(&cnt[d4.x], 1);
        if ((unsigned)d4.y < (unsigned)N) atomicAdd(&cnt[d4.y], 1);
        if ((unsigned)d4.z < (unsigned)N) atomicAdd(&cnt[d4.z], 1);
        if ((unsigned)d4.w < (unsigned)N) atomicAdd(&cnt[d4.w], 1);
    } else {
        for (int j = base; j < E; ++j) {
            int d = dst[j];
            if ((unsigned)d < (unsigned)N) atomicAdd(&cnt[d], 1);
        }
    }
}

// exclusive scan of (cnt[i] + 1)  [+1 = self loop], 1024 elements per block
__global__ __launch_bounds__(256) void scan1_k(const int* __restrict__ cnt, int N,
                                               int* __restrict__ rowptr, int* __restrict__ bsum) {
    __shared__ int tl[256];
    int base = blockIdx.x * 1024 + threadIdx.x * 4;
    int v[4];
    int run = 0;
    for (int j = 0; j < 4; ++j) {
        int idx = base + j;
        int x = (idx < N) ? (cnt[idx] + 1) : 0;
        v[j] = run;
        run += x;
    }
    tl[threadIdx.x] = run;
    __syncthreads();
    for (int off = 1; off < 256; off <<= 1) {
        int t = (threadIdx.x >= off) ? tl[threadIdx.x - off] : 0;
        __syncthreads();
        tl[threadIdx.x] += t;
        __syncthreads();
    }
    int excl = (threadIdx.x == 0) ? 0 : tl[threadIdx.x - 1];
    for (int j = 0; j < 4; ++j) {
        int idx = base + j;
        if (idx < N) rowptr[idx] = excl + v[j];
    }
    if (threadIdx.x == 255) bsum[blockIdx.x] = tl[255];
}

__global__ __launch_bounds__(256) void scan2_k(int* __restrict__ bsum, int nb) {
    __shared__ int tl[256];
    int x = (threadIdx.x < nb) ? bsum[threadIdx.x] : 0;
    tl[threadIdx.x] = x;
    __syncthreads();
    for (int off = 1; off < 256; off <<= 1) {
        int t = (threadIdx.x >= off) ? tl[threadIdx.x - off] : 0;
        __syncthreads();
        tl[threadIdx.x] += t;
        __syncthreads();
    }
    int excl = (threadIdx.x == 0) ? 0 : tl[threadIdx.x - 1];
    if (threadIdx.x < nb) bsum[threadIdx.x] = excl;
}

__global__ __launch_bounds__(256) void scan3_k(int* __restrict__ rowptr, const int* __restrict__ bsum,
                                               int N, int total) {
    int i = blockIdx.x * 256 + threadIdx.x;
    if (i < N) rowptr[i] += bsum[i >> 10];
    if (i == N) rowptr[N] = total;
}

__global__ __launch_bounds__(256) void fill_k(const int* __restrict__ srcI, const int* __restrict__ dstI,
                                              int E, int N, const int* __restrict__ rowptr,
                                              int* __restrict__ cursor, int* __restrict__ colA,
                                              int* __restrict__ rowid) {
    int i = blockIdx.x * 256 + threadIdx.x;
    int M = E + N;
    if (i >= M) return;
    int s, d;
    if (i < E) {
        s = srcI[i];
        d = dstI[i];
    } else {
        s = i - E;  // self loop
        d = s;
    }
    if ((unsigned)d < (unsigned)N && (unsigned)s < (unsigned)N) {
        int p = rowptr[d] + atomicAdd(&cursor[d], 1);
        if (p < M) {
            colA[p] = s;
            rowid[p] = d;
        }
    }
}

// ---------------- h = X @ W (8x8 register tile), plus alpha_src / alpha_dst ----------------
// Block 256 threads as 16x16: thread (tr=tid>>4, tc=tid&15) computes rows tr*8..+7,
// cols tc*8..+7 of a 128x128 tile. K chunked by 32. Per k: 4x ds_read_b128 -> 64 FMA
// (1.0 B LDS per FMA, vs 1.5 in the old 8x4 tile).

__global__ __launch_bounds__(256) void gemm_alpha_k(const float* __restrict__ X, const float* __restrict__ W,
                                                    const float* __restrict__ a_s, const float* __restrict__ a_d,
                                                    float* __restrict__ Hout, float* __restrict__ asrc,
                                                    float* __restrict__ adst, int N) {
    __shared__ float Xt[32][132];   // [k][row 0..127], pad 132 (16B-aligned rows, conflict-free b128 reads)
    __shared__ float Wl[32][128];
    const int tid = threadIdx.x;
    const int rowBase = blockIdx.x * 128;
    const int tr = tid >> 4;   // 0..15
    const int tc = tid & 15;   // 0..15

    float acc[8][8];
#pragma unroll
    for (int i = 0; i < 8; ++i)
#pragma unroll
        for (int c = 0; c < 8; ++c) acc[i][c] = 0.f;

    for (int kc = 0; kc < 128; kc += 32) {
        // stage X chunk transposed: 128 rows x 32 k = 1024 float4
#pragma unroll
        for (int j = 0; j < 4; ++j) {
            int f = tid + 256 * j;       // 0..1023
            int r = f >> 3;              // 0..127
            int kq = (f & 7) * 4;        // 0..28
            int gr = rowBase + r;
            float4 xv = make_float4(0.f, 0.f, 0.f, 0.f);
            if (gr < N) xv = *(const float4*)&X[(size_t)gr * 128 + kc + kq];
            Xt[kq + 0][r] = xv.x;
            Xt[kq + 1][r] = xv.y;
            Xt[kq + 2][r] = xv.z;
            Xt[kq + 3][r] = xv.w;
        }
        // stage W chunk row-major: 32 k x 128 cols = 1024 float4
#pragma unroll
        for (int j = 0; j < 4; ++j) {
            int f = tid + 256 * j;       // 0..1023
            int k = f >> 5;              // 0..31
            int c4 = (f & 31) * 4;       // 0..124
            *(float4*)&Wl[k][c4] = *(const float4*)&W[(size_t)(kc + k) * 128 + c4];
        }
        __syncthreads();

#pragma unroll
        for (int k = 0; k < 32; ++k) {
            float4 x0 = *(const float4*)&Xt[k][tr * 8];
            float4 x1 = *(const float4*)&Xt[k][tr * 8 + 4];
            float4 w0 = *(const float4*)&Wl[k][tc * 8];
            float4 w1 = *(const float4*)&Wl[k][tc * 8 + 4];
            const float xs[8] = {x0.x, x0.y, x0.z, x0.w, x1.x, x1.y, x1.z, x1.w};
            const float ws[8] = {w0.x, w0.y, w0.z, w0.w, w1.x, w1.y, w1.z, w1.w};
#pragma unroll
            for (int i = 0; i < 8; ++i)
#pragma unroll
                for (int c = 0; c < 8; ++c) acc[i][c] = fmaf(xs[i], ws[c], acc[i][c]);
        }
        __syncthreads();
    }

    // epilogue: cols tc*8..+7 lie within head (tc>>2); reduce alpha over the 4
    // col-threads (tc&3) covering one 32-col head via width-4 shuffles.
    float4 as0 = *(const float4*)&a_s[tc * 8];
    float4 as1 = *(const float4*)&a_s[tc * 8 + 4];
    float4 ad0 = *(const float4*)&a_d[tc * 8];
    float4 ad1 = *(const float4*)&a_d[tc * 8 + 4];
    const int head = tc >> 2;

#pragma unroll
    for (int i = 0; i < 8; ++i) {
        float ps = acc[i][0] * as0.x + acc[i][1] * as0.y + acc[i][2] * as0.z + acc[i][3] * as0.w +
                   acc[i][4] * as1.x + acc[i][5] * as1.y + acc[i][6] * as1.z + acc[i][7] * as1.w;
        float pd = acc[i][0] * ad0.x + acc[i][1] * ad0.y + acc[i][2] * ad0.z + acc[i][3] * ad0.w +
                   acc[i][4] * ad1.x + acc[i][5] * ad1.y + acc[i][6] * ad1.z + acc[i][7] * ad1.w;
        ps += __shfl_down(ps, 1, 4);
        ps += __shfl_down(ps, 2, 4);
        pd += __shfl_down(pd, 1, 4);
        pd += __shfl_down(pd, 2, 4);
        int gr = rowBase + tr * 8 + i;
        if (gr < N) {
            *(float4*)&Hout[(size_t)gr * 128 + tc * 8] =
                make_float4(acc[i][0], acc[i][1], acc[i][2], acc[i][3]);
            *(float4*)&Hout[(size_t)gr * 128 + tc * 8 + 4] =
                make_float4(acc[i][4], acc[i][5], acc[i][6], acc[i][7]);
            if ((tc & 3) == 0) {
                asrc[gr * 4 + head] = ps;
                adst[gr * 4 + head] = pd;
            }
        }
    }
}

// ---------------- edge-parallel unnormalized weights (no atomics) ----------------

__global__ __launch_bounds__(256) void wgt_k(const int* __restrict__ colA, const int* __restrict__ rowid,
                                             const float* __restrict__ asrc, const float* __restrict__ adst,
                                             float* __restrict__ wgtA, int M) {
    int p = blockIdx.x * 256 + threadIdx.x;
    if (p >= M) return;
    int s = colA[p];
    int d = rowid[p];
    float4 as = *(const float4*)&asrc[s * 4];
    float4 ad = *(const float4*)&adst[d * 4];
    float4 w;
    w.x = __expf(lrelu(as.x + ad.x));
    w.y = __expf(lrelu(as.y + ad.y));
    w.z = __expf(lrelu(as.z + ad.z));
    w.w = __expf(lrelu(as.w + ad.w));
    *(float4*)&wgtA[(size_t)p * 4] = w;
}

// ---------------- aggregation: one wave per dst node, unroll x16/x8/x4 ----------------

__global__ __launch_bounds__(256) void aggregate_k(const float* __restrict__ Hbuf,
                                                   const float* __restrict__ wgtA,
                                                   const int* __restrict__ rowptr,
                                                   const int* __restrict__ colA,
                                                   const float* __restrict__ bias,
                                                   float* __restrict__ out, int N) {
    int wave = (blockIdx.x * 256 + threadIdx.x) >> 6;
    int lane = threadIdx.x & 63;
    if (wave >= N) return;
    int n = wave;
    int c0 = lane * 2;
    int head = c0 >> 5;
    float acc0 = 0.f, acc1 = 0.f, sw = 0.f;
    int b = rowptr[n], e = rowptr[n + 1];
    int p = b;
    for (; p + 16 <= e; p += 16) {
        int s[16];
#pragma unroll
        for (int j = 0; j < 16; ++j) s[j] = colA[p + j];
        float w[16];
#pragma unroll
        for (int j = 0; j < 16; ++j) w[j] = wgtA[(size_t)(p + j) * 4 + head];
        float2 h[16];
#pragma unroll
        for (int j = 0; j < 16; ++j) h[j] = *(const float2*)&Hbuf[(size_t)s[j] * 128 + c0];
#pragma unroll
        for (int j = 0; j < 16; ++j) {
            sw += w[j];
            acc0 = fmaf(w[j], h[j].x, acc0);
            acc1 = fmaf(w[j], h[j].y, acc1);
        }
    }
    for (; p + 8 <= e; p += 8) {
        int s[8];
#pragma unroll
        for (int j = 0; j < 8; ++j) s[j] = colA[p + j];
        float w[8];
#pragma unroll
        for (int j = 0; j < 8; ++j) w[j] = wgtA[(size_t)(p + j) * 4 + head];
        float2 h[8];
#pragma unroll
        for (int j = 0; j < 8; ++j) h[j] = *(const float2*)&Hbuf[(size_t)s[j] * 128 + c0];
#pragma unroll
        for (int j = 0; j < 8; ++j) {
            sw += w[j];
            acc0 = fmaf(w[j], h[j].x, acc0);
            acc1 = fmaf(w[j], h[j].y, acc1);
        }
    }
    for (; p + 4 <= e; p += 4) {
        int s[4];
#pragma unroll
        for (int j = 0; j < 4; ++j) s[j] = colA[p + j];
        float w[4];
#pragma unroll
        for (int j = 0; j < 4; ++j) w[j] = wgtA[(size_t)(p + j) * 4 + head];
        float2 h[4];
#pragma unroll
        for (int j = 0; j < 4; ++j) h[j] = *(const float2*)&Hbuf[(size_t)s[j] * 128 + c0];
#pragma unroll
        for (int j = 0; j < 4; ++j) {
            sw += w[j];
            acc0 = fmaf(w[j], h[j].x, acc0);
            acc1 = fmaf(w[j], h[j].y, acc1);
        }
    }
    for (; p < e; ++p) {
        int s = colA[p];
        float w = wgtA[(size_t)p * 4 + head];
        float2 hv = *(const float2*)&Hbuf[(size_t)s * 128 + c0];
        sw += w;
        acc0 = fmaf(w, hv.x, acc0);
        acc1 = fmaf(w, hv.y, acc1);
    }
    float inv_dh = 1.f / sw;
    float o0 = fmaxf(acc0 * inv_dh + bias[c0], 0.f);
    float o1 = fmaxf(acc1 * inv_dh + bias[c0 + 1], 0.f);
    *(float2*)&out[(size_t)n * 128 + c0] = make_float2(o0, o1);
}

// ---------------- launch ----------------

extern "C" void kernel_launch(void* const* d_in, const int* in_sizes, int n_in,
                              void* d_out, int out_size, void* d_ws, size_t ws_size,
                              hipStream_t stream) {
    const float* X   = (const float*)d_in[0];
    const int*   EI  = (const int*)d_in[1];
    const float* W1  = (const float*)d_in[2];
    const float* as1 = (const float*)d_in[3];
    const float* ad1 = (const float*)d_in[4];
    const float* b1  = (const float*)d_in[5];
    const float* W2  = (const float*)d_in[6];
    const float* as2 = (const float*)d_in[7];
    const float* ad2 = (const float*)d_in[8];
    const float* b2  = (const float*)d_in[9];

    const int N = in_sizes[0] / 128;
    const int E = in_sizes[1] / 2;
    const int M = E + N;
    const int* srcI = EI;
    const int* dstI = EI + E;

    char* w = (char*)d_ws;
    auto alloc = [&](size_t bytes) {
        char* p = w;
        w += (bytes + 255) & ~(size_t)255;
        return p;
    };
    float* Hbuf   = (float*)alloc((size_t)N * 128 * 4);
    float* wgtA   = (float*)alloc((size_t)M * 4 * 4);
    float* asrc   = (float*)alloc((size_t)N * 4 * 4);
    float* adst   = (float*)alloc((size_t)N * 4 * 4);
    int*   cnt    = (int*)alloc((size_t)N * 4);      // cnt+cursor contiguous: one memset
    int*   cursor = (int*)alloc((size_t)N * 4);
    int*   rowptr = (int*)alloc((size_t)(N + 1) * 4);
    int*   colA   = (int*)alloc((size_t)M * 4);
    int*   rowid  = (int*)alloc((size_t)M * 4);
    int*   bsum   = (int*)alloc(1024 * 4);

    hipMemsetAsync(cnt, 0, (char*)(cursor + N) - (char*)cnt, stream);

    // CSR build (shared by both layers)
    count_deg_k<<<(E / 4 + 256) / 256, 256, 0, stream>>>(dstI, E, N, cnt);
    int nb1 = (N + 1023) / 1024;
    scan1_k<<<nb1, 256, 0, stream>>>(cnt, N, rowptr, bsum);
    scan2_k<<<1, 256, 0, stream>>>(bsum, nb1);
    scan3_k<<<(N + 1 + 255) / 256, 256, 0, stream>>>(rowptr, bsum, N, M);
    fill_k<<<(M + 255) / 256, 256, 0, stream>>>(srcI, dstI, E, N, rowptr, cursor, colA, rowid);

    float* out = (float*)d_out;

    // layer 1 (activation staged in d_out)
    gemm_alpha_k<<<(N + 127) / 128, 256, 0, stream>>>(X, W1, as1, ad1, Hbuf, asrc, adst, N);
    wgt_k<<<(M + 255) / 256, 256, 0, stream>>>(colA, rowid, asrc, adst, wgtA, M);
    aggregate_k<<<((size_t)N * 64 + 255) / 256, 256, 0, stream>>>(Hbuf, wgtA, rowptr, colA, b1, out, N);
    // layer 2
    gemm_alpha_k<<<(N + 127) / 128, 256, 0, stream>>>(out, W2, as2, ad2, Hbuf, asrc, adst, N);
    wgt_k<<<(M + 255) / 256, 256, 0, stream>>>(colA, rowid, asrc, adst, wgtA, M);
    aggregate_k<<<((size_t)N * 64 + 255) / 256, 256, 0, stream>>>(Hbuf, wgtA, rowptr, colA, b2, out, N);
}

// Round 7
// 558.721 us; speedup vs baseline: 1.2064x; 1.2064x over previous
//
#include <hip/hip_runtime.h>
#include <cstdint>
#include <cstddef>

#define NEG_SLOPE 0.2f

static __device__ __forceinline__ float lrelu(float v) { return v > 0.f ? v : NEG_SLOPE * v; }

// pack two fp32 -> two bf16 (RTNE) in one uint
static __device__ __forceinline__ unsigned pack_bf2(float a, float b) {
    unsigned ua = __float_as_uint(a);
    unsigned ub = __float_as_uint(b);
    ua = (ua + 0x7fffu + ((ua >> 16) & 1u)) >> 16;
    ub = (ub + 0x7fffu + ((ub >> 16) & 1u)) >> 16;
    return ua | (ub << 16);
}

// ---------------- CSR build ----------------

__global__ __launch_bounds__(256) void count_deg_k(const int* __restrict__ dst, int E, int N,
                                                   int* __restrict__ cnt) {
    int i = blockIdx.x * 256 + threadIdx.x;
    int base = i * 4;
    if (base + 4 <= E) {
        int4 d4 = *(const int4*)&dst[base];
        if ((unsigned)d4.x < (unsigned)N) atomicAdd(&cnt[d4.x], 1);
        if ((unsigned)d4.y < (unsigned)N) atomicAdd(&cnt[d4.y], 1);
        if ((unsigned)d4.z < (unsigned)N) atomicAdd(&cnt[d4.z], 1);
        if ((unsigned)d4.w < (unsigned)N) atomicAdd(&cnt[d4.w], 1);
    } else {
        for (int j = base; j < E; ++j) {
            int d = dst[j];
            if ((unsigned)d < (unsigned)N) atomicAdd(&cnt[d], 1);
        }
    }
}

// exclusive scan of (cnt[i] + 1)  [+1 = self loop], 1024 elements per block
__global__ __launch_bounds__(256) void scan1_k(const int* __restrict__ cnt, int N,
                                               int* __restrict__ rowptr, int* __restrict__ bsum) {
    __shared__ int tl[256];
    int base = blockIdx.x * 1024 + threadIdx.x * 4;
    int v[4];
    int run = 0;
    for (int j = 0; j < 4; ++j) {
        int idx = base + j;
        int x = (idx < N) ? (cnt[idx] + 1) : 0;
        v[j] = run;
        run += x;
    }
    tl[threadIdx.x] = run;
    __syncthreads();
    for (int off = 1; off < 256; off <<= 1) {
        int t = (threadIdx.x >= off) ? tl[threadIdx.x - off] : 0;
        __syncthreads();
        tl[threadIdx.x] += t;
        __syncthreads();
    }
    int excl = (threadIdx.x == 0) ? 0 : tl[threadIdx.x - 1];
    for (int j = 0; j < 4; ++j) {
        int idx = base + j;
        if (idx < N) rowptr[idx] = excl + v[j];
    }
    if (threadIdx.x == 255) bsum[blockIdx.x] = tl[255];
}

__global__ __launch_bounds__(256) void scan2_k(int* __restrict__ bsum, int nb) {
    __shared__ int tl[256];
    int x = (threadIdx.x < nb) ? bsum[threadIdx.x] : 0;
    tl[threadIdx.x] = x;
    __syncthreads();
    for (int off = 1; off < 256; off <<= 1) {
        int t = (threadIdx.x >= off) ? tl[threadIdx.x - off] : 0;
        __syncthreads();
        tl[threadIdx.x] += t;
        __syncthreads();
    }
    int excl = (threadIdx.x == 0) ? 0 : tl[threadIdx.x - 1];
    if (threadIdx.x < nb) bsum[threadIdx.x] = excl;
}

__global__ __launch_bounds__(256) void scan3_k(int* __restrict__ rowptr, const int* __restrict__ bsum,
                                               int N, int total) {
    int i = blockIdx.x * 256 + threadIdx.x;
    if (i < N) rowptr[i] += bsum[i >> 10];
    if (i == N) rowptr[N] = total;
}

// packed (src,dst) per CSR slot: one 8B store instead of two scattered 4B stores
__global__ __launch_bounds__(256) void fill_k(const int* __restrict__ srcI, const int* __restrict__ dstI,
                                              int E, int N, const int* __restrict__ rowptr,
                                              int* __restrict__ cursor, int2* __restrict__ colRow) {
    int i = blockIdx.x * 256 + threadIdx.x;
    int M = E + N;
    if (i >= M) return;
    int s, d;
    if (i < E) {
        s = srcI[i];
        d = dstI[i];
    } else {
        s = i - E;  // self loop
        d = s;
    }
    if ((unsigned)d < (unsigned)N && (unsigned)s < (unsigned)N) {
        int p = rowptr[d] + atomicAdd(&cursor[d], 1);
        if (p < M) colRow[p] = make_int2(s, d);
    }
}

// ---------------- h = X @ W (register-tiled, r5-proven), bf16 Hout + fp32 alphas ----------------

__global__ __launch_bounds__(256) void gemm_alpha_k(const float* __restrict__ X, const float* __restrict__ W,
                                                    const float* __restrict__ a_s, const float* __restrict__ a_d,
                                                    unsigned short* __restrict__ Hout, float* __restrict__ asrc,
                                                    float* __restrict__ adst, int N) {
    __shared__ float Xt[32][68];   // [k][row], pad 68 keeps 16B alignment
    __shared__ float Wl[32][128];
    const int tid = threadIdx.x;
    const int rowBase = blockIdx.x * 64;
    const int tr = tid >> 5;   // 0..7
    const int tc = tid & 31;   // 0..31

    float acc[8][4];
#pragma unroll
    for (int i = 0; i < 8; ++i)
#pragma unroll
        for (int c = 0; c < 4; ++c) acc[i][c] = 0.f;

    for (int kc = 0; kc < 128; kc += 32) {
#pragma unroll
        for (int j = 0; j < 2; ++j) {
            int f = tid + 256 * j;       // 0..511
            int r = f >> 3;              // 0..63
            int kq = (f & 7) * 4;        // 0..28
            int gr = rowBase + r;
            float4 xv = make_float4(0.f, 0.f, 0.f, 0.f);
            if (gr < N) xv = *(const float4*)&X[(size_t)gr * 128 + kc + kq];
            Xt[kq + 0][r] = xv.x;
            Xt[kq + 1][r] = xv.y;
            Xt[kq + 2][r] = xv.z;
            Xt[kq + 3][r] = xv.w;
        }
#pragma unroll
        for (int j = 0; j < 4; ++j) {
            int f = tid + 256 * j;       // 0..1023
            int k = f >> 5;              // 0..31
            int c4 = (f & 31) * 4;       // 0..124
            *(float4*)&Wl[k][c4] = *(const float4*)&W[(size_t)(kc + k) * 128 + c4];
        }
        __syncthreads();

#pragma unroll
        for (int k = 0; k < 32; ++k) {
            float4 x0 = *(const float4*)&Xt[k][tr * 8];
            float4 x1 = *(const float4*)&Xt[k][tr * 8 + 4];
            float4 wv = *(const float4*)&Wl[k][tc * 4];
            const float xs[8] = {x0.x, x0.y, x0.z, x0.w, x1.x, x1.y, x1.z, x1.w};
#pragma unroll
            for (int i = 0; i < 8; ++i) {
                acc[i][0] = fmaf(xs[i], wv.x, acc[i][0]);
                acc[i][1] = fmaf(xs[i], wv.y, acc[i][1]);
                acc[i][2] = fmaf(xs[i], wv.z, acc[i][2]);
                acc[i][3] = fmaf(xs[i], wv.w, acc[i][3]);
            }
        }
        __syncthreads();
    }

    float4 asv = *(const float4*)&a_s[tc * 4];
    float4 adv = *(const float4*)&a_d[tc * 4];
    const int head = tc >> 3;

#pragma unroll
    for (int i = 0; i < 8; ++i) {
        float ps = acc[i][0] * asv.x + acc[i][1] * asv.y + acc[i][2] * asv.z + acc[i][3] * asv.w;
        float pd = acc[i][0] * adv.x + acc[i][1] * adv.y + acc[i][2] * adv.z + acc[i][3] * adv.w;
        ps += __shfl_down(ps, 4, 8);
        ps += __shfl_down(ps, 2, 8);
        ps += __shfl_down(ps, 1, 8);
        pd += __shfl_down(pd, 4, 8);
        pd += __shfl_down(pd, 2, 8);
        pd += __shfl_down(pd, 1, 8);
        int gr = rowBase + tr * 8 + i;
        if (gr < N) {
            uint2 pk = make_uint2(pack_bf2(acc[i][0], acc[i][1]), pack_bf2(acc[i][2], acc[i][3]));
            *(uint2*)&Hout[(size_t)gr * 128 + tc * 4] = pk;
            if ((tid & 7) == 0) {
                asrc[gr * 4 + head] = ps;
                adst[gr * 4 + head] = pd;
            }
        }
    }
}

// ---------------- edge-parallel unnormalized weights (no atomics) ----------------
// No max-subtraction: logits are O(few) for this model scale, exp() is fp32-safe.

__global__ __launch_bounds__(256) void wgt_k(const int2* __restrict__ colRow,
                                             const float* __restrict__ asrc, const float* __restrict__ adst,
                                             float* __restrict__ wgtA, int M) {
    int p = blockIdx.x * 256 + threadIdx.x;
    if (p >= M) return;
    int2 sd = colRow[p];
    float4 as = *(const float4*)&asrc[sd.x * 4];
    float4 ad = *(const float4*)&adst[sd.y * 4];
    float4 w;
    w.x = __expf(lrelu(as.x + ad.x));
    w.y = __expf(lrelu(as.y + ad.y));
    w.z = __expf(lrelu(as.z + ad.z));
    w.w = __expf(lrelu(as.w + ad.w));
    *(float4*)&wgtA[(size_t)p * 4] = w;
}

// ---------------- aggregation: one wave per dst node, unroll x8, bf16 h gathers ----------------
// Denominator accumulated in-register (free). h rows are bf16: 256B/row gathered
// instead of 512B -> half the L2/L3 miss count (the latency-bound resource).

__global__ __launch_bounds__(256) void aggregate_k(const unsigned short* __restrict__ Hbuf,
                                                   const float* __restrict__ wgtA,
                                                   const int* __restrict__ rowptr,
                                                   const int2* __restrict__ colRow,
                                                   const float* __restrict__ bias,
                                                   float* __restrict__ out, int N) {
    int wave = (blockIdx.x * 256 + threadIdx.x) >> 6;
    int lane = threadIdx.x & 63;
    if (wave >= N) return;
    int n = wave;
    int c0 = lane * 2;
    int head = c0 >> 5;
    float acc0 = 0.f, acc1 = 0.f, sw = 0.f;
    int b = rowptr[n], e = rowptr[n + 1];
    int p = b;
    for (; p + 8 <= e; p += 8) {
        int s[8];
#pragma unroll
        for (int j = 0; j < 8; ++j) s[j] = colRow[p + j].x;
        float w[8];
#pragma unroll
        for (int j = 0; j < 8; ++j) w[j] = wgtA[(size_t)(p + j) * 4 + head];
        unsigned hu[8];
#pragma unroll
        for (int j = 0; j < 8; ++j) hu[j] = *(const unsigned*)&Hbuf[(size_t)s[j] * 128 + c0];
#pragma unroll
        for (int j = 0; j < 8; ++j) {
            float h0 = __uint_as_float(hu[j] << 16);
            float h1 = __uint_as_float(hu[j] & 0xffff0000u);
            sw += w[j];
            acc0 = fmaf(w[j], h0, acc0);
            acc1 = fmaf(w[j], h1, acc1);
        }
    }
    for (; p + 2 <= e; p += 2) {
        int s0 = colRow[p].x, s1 = colRow[p + 1].x;
        float w0 = wgtA[(size_t)p * 4 + head];
        float w1 = wgtA[(size_t)(p + 1) * 4 + head];
        unsigned u0 = *(const unsigned*)&Hbuf[(size_t)s0 * 128 + c0];
        unsigned u1 = *(const unsigned*)&Hbuf[(size_t)s1 * 128 + c0];
        sw += w0 + w1;
        acc0 = fmaf(w0, __uint_as_float(u0 << 16), acc0);
        acc1 = fmaf(w0, __uint_as_float(u0 & 0xffff0000u), acc1);
        acc0 = fmaf(w1, __uint_as_float(u1 << 16), acc0);
        acc1 = fmaf(w1, __uint_as_float(u1 & 0xffff0000u), acc1);
    }
    for (; p < e; ++p) {
        int s = colRow[p].x;
        float w = wgtA[(size_t)p * 4 + head];
        unsigned u = *(const unsigned*)&Hbuf[(size_t)s * 128 + c0];
        sw += w;
        acc0 = fmaf(w, __uint_as_float(u << 16), acc0);
        acc1 = fmaf(w, __uint_as_float(u & 0xffff0000u), acc1);
    }
    float inv_dh = 1.f / sw;
    float o0 = fmaxf(acc0 * inv_dh + bias[c0], 0.f);
    float o1 = fmaxf(acc1 * inv_dh + bias[c0 + 1], 0.f);
    *(float2*)&out[(size_t)n * 128 + c0] = make_float2(o0, o1);
}

// ---------------- launch ----------------

extern "C" void kernel_launch(void* const* d_in, const int* in_sizes, int n_in,
                              void* d_out, int out_size, void* d_ws, size_t ws_size,
                              hipStream_t stream) {
    const float* X   = (const float*)d_in[0];
    const int*   EI  = (const int*)d_in[1];
    const float* W1  = (const float*)d_in[2];
    const float* as1 = (const float*)d_in[3];
    const float* ad1 = (const float*)d_in[4];
    const float* b1  = (const float*)d_in[5];
    const float* W2  = (const float*)d_in[6];
    const float* as2 = (const float*)d_in[7];
    const float* ad2 = (const float*)d_in[8];
    const float* b2  = (const float*)d_in[9];

    const int N = in_sizes[0] / 128;
    const int E = in_sizes[1] / 2;
    const int M = E + N;
    const int* srcI = EI;
    const int* dstI = EI + E;

    char* w = (char*)d_ws;
    auto alloc = [&](size_t bytes) {
        char* p = w;
        w += (bytes + 255) & ~(size_t)255;
        return p;
    };
    unsigned short* Hbuf = (unsigned short*)alloc((size_t)N * 128 * 2);  // bf16
    float* wgtA   = (float*)alloc((size_t)M * 4 * 4);
    float* asrc   = (float*)alloc((size_t)N * 4 * 4);
    float* adst   = (float*)alloc((size_t)N * 4 * 4);
    int*   cnt    = (int*)alloc((size_t)N * 4);      // cnt+cursor contiguous: one memset
    int*   cursor = (int*)alloc((size_t)N * 4);
    int*   rowptr = (int*)alloc((size_t)(N + 1) * 4);
    int2*  colRow = (int2*)alloc((size_t)M * 8);
    int*   bsum   = (int*)alloc(1024 * 4);

    hipMemsetAsync(cnt, 0, (char*)(cursor + N) - (char*)cnt, stream);

    // CSR build (shared by both layers)
    count_deg_k<<<(E / 4 + 256) / 256, 256, 0, stream>>>(dstI, E, N, cnt);
    int nb1 = (N + 1023) / 1024;
    scan1_k<<<nb1, 256, 0, stream>>>(cnt, N, rowptr, bsum);
    scan2_k<<<1, 256, 0, stream>>>(bsum, nb1);
    scan3_k<<<(N + 1 + 255) / 256, 256, 0, stream>>>(rowptr, bsum, N, M);
    fill_k<<<(M + 255) / 256, 256, 0, stream>>>(srcI, dstI, E, N, rowptr, cursor, colRow);

    float* out = (float*)d_out;

    // layer 1 (activation staged in d_out, fp32)
    gemm_alpha_k<<<(N + 63) / 64, 256, 0, stream>>>(X, W1, as1, ad1, Hbuf, asrc, adst, N);
    wgt_k<<<(M + 255) / 256, 256, 0, stream>>>(colRow, asrc, adst, wgtA, M);
    aggregate_k<<<((size_t)N * 64 + 255) / 256, 256, 0, stream>>>(Hbuf, wgtA, rowptr, colRow, b1, out, N);
    // layer 2
    gemm_alpha_k<<<(N + 63) / 64, 256, 0, stream>>>(out, W2, as2, ad2, Hbuf, asrc, adst, N);
    wgt_k<<<(M + 255) / 256, 256, 0, stream>>>(colRow, asrc, adst, wgtA, M);
    aggregate_k<<<((size_t)N * 64 + 255) / 256, 256, 0, stream>>>(Hbuf, wgtA, rowptr, colRow, b2, out, N);
}

// Round 8
// 513.153 us; speedup vs baseline: 1.3135x; 1.0888x over previous
//
#include <hip/hip_runtime.h>
#include <cstdint>
#include <cstddef>

#define NEG_SLOPE 0.2f
#define BIN_SHIFT 9   // 512 nodes per bucket

static __device__ __forceinline__ float lrelu(float v) { return v > 0.f ? v : NEG_SLOPE * v; }

// pack two fp32 -> two bf16 (RTNE) in one uint
static __device__ __forceinline__ unsigned pack_bf2(float a, float b) {
    unsigned ua = __float_as_uint(a);
    unsigned ub = __float_as_uint(b);
    ua = (ua + 0x7fffu + ((ua >> 16) & 1u)) >> 16;
    ub = (ub + 0x7fffu + ((ub >> 16) & 1u)) >> 16;
    return ua | (ub << 16);
}

// ---------------- CSR build ----------------

__global__ __launch_bounds__(256) void count_deg_k(const int* __restrict__ dst, int E, int N,
                                                   int* __restrict__ cnt) {
    int i = blockIdx.x * 256 + threadIdx.x;
    int base = i * 4;
    if (base + 4 <= E) {
        int4 d4 = *(const int4*)&dst[base];
        if ((unsigned)d4.x < (unsigned)N) atomicAdd(&cnt[d4.x], 1);
        if ((unsigned)d4.y < (unsigned)N) atomicAdd(&cnt[d4.y], 1);
        if ((unsigned)d4.z < (unsigned)N) atomicAdd(&cnt[d4.z], 1);
        if ((unsigned)d4.w < (unsigned)N) atomicAdd(&cnt[d4.w], 1);
    } else {
        for (int j = base; j < E; ++j) {
            int d = dst[j];
            if ((unsigned)d < (unsigned)N) atomicAdd(&cnt[d], 1);
        }
    }
}

// exclusive scan of (cnt[i] + 1)  [+1 = self loop], 1024 elements per block
__global__ __launch_bounds__(256) void scan1_k(const int* __restrict__ cnt, int N,
                                               int* __restrict__ rowptr, int* __restrict__ bsum) {
    __shared__ int tl[256];
    int base = blockIdx.x * 1024 + threadIdx.x * 4;
    int v[4];
    int run = 0;
    for (int j = 0; j < 4; ++j) {
        int idx = base + j;
        int x = (idx < N) ? (cnt[idx] + 1) : 0;
        v[j] = run;
        run += x;
    }
    tl[threadIdx.x] = run;
    __syncthreads();
    for (int off = 1; off < 256; off <<= 1) {
        int t = (threadIdx.x >= off) ? tl[threadIdx.x - off] : 0;
        __syncthreads();
        tl[threadIdx.x] += t;
        __syncthreads();
    }
    int excl = (threadIdx.x == 0) ? 0 : tl[threadIdx.x - 1];
    for (int j = 0; j < 4; ++j) {
        int idx = base + j;
        if (idx < N) rowptr[idx] = excl + v[j];
    }
    if (threadIdx.x == 255) bsum[blockIdx.x] = tl[255];
}

__global__ __launch_bounds__(256) void scan2_k(int* __restrict__ bsum, int nb) {
    __shared__ int tl[256];
    int x = (threadIdx.x < nb) ? bsum[threadIdx.x] : 0;
    tl[threadIdx.x] = x;
    __syncthreads();
    for (int off = 1; off < 256; off <<= 1) {
        int t = (threadIdx.x >= off) ? tl[threadIdx.x - off] : 0;
        __syncthreads();
        tl[threadIdx.x] += t;
        __syncthreads();
    }
    int excl = (threadIdx.x == 0) ? 0 : tl[threadIdx.x - 1];
    if (threadIdx.x < nb) bsum[threadIdx.x] = excl;
}

__global__ __launch_bounds__(256) void scan3_k(int* __restrict__ rowptr, const int* __restrict__ bsum,
                                               int N, int total) {
    int i = blockIdx.x * 256 + threadIdx.x;
    if (i < N) rowptr[i] += bsum[i >> 10];
    if (i == N) rowptr[N] = total;
}

// bucketCursor[b] starts at the CSR base of the bucket's node range
__global__ __launch_bounds__(256) void init_bcur_k(const int* __restrict__ rowptr,
                                                   int* __restrict__ bucketCursor, int K) {
    int b = blockIdx.x * 256 + threadIdx.x;
    if (b < K) bucketCursor[b] = rowptr[b << BIN_SHIFT];
}

// Phase A: bin edges (incl. self-loops) into coarse dst-range buckets, dense writes.
// Block handles 4096 edges; LDS histogram -> one global atomic per bucket -> dense ranked writes.
__global__ __launch_bounds__(256) void bin_k(const int* __restrict__ srcI, const int* __restrict__ dstI,
                                             int E, int N, int K, int* __restrict__ bucketCursor,
                                             int2* __restrict__ tmpE) {
    __shared__ int hist[256];
    __shared__ int lbase[256];
    const int t = threadIdx.x;
    const int M = E + N;
    const int chunk0 = blockIdx.x * 4096;
    hist[t] = 0;
    __syncthreads();

    int s[16], d[16], b[16];
#pragma unroll
    for (int j = 0; j < 16; ++j) {
        int i = chunk0 + t + j * 256;
        b[j] = -1;
        if (i < M) {
            int ss, dd;
            if (i < E) { ss = srcI[i]; dd = dstI[i]; }
            else       { ss = i - E;  dd = ss; }
            if ((unsigned)dd < (unsigned)N && (unsigned)ss < (unsigned)N) {
                s[j] = ss; d[j] = dd; b[j] = dd >> BIN_SHIFT;
                atomicAdd(&hist[b[j]], 1);
            }
        }
    }
    __syncthreads();
    if (t < K) {
        int c = hist[t];
        lbase[t] = (c > 0) ? atomicAdd(&bucketCursor[t], c) : 0;
    }
    hist[t] = 0;   // safe: each index touched only by its own thread before the next barrier
    __syncthreads();
#pragma unroll
    for (int j = 0; j < 16; ++j) {
        if (b[j] >= 0) {
            int r = atomicAdd(&hist[b[j]], 1);
            tmpE[lbase[b[j]] + r] = make_int2(s[j], d[j]);
        }
    }
}

// Phase B: one block per bucket; scatter within an L2-resident contiguous slot region.
__global__ __launch_bounds__(256) void scatter_k(const int2* __restrict__ tmpE,
                                                 const int* __restrict__ rowptr,
                                                 int* __restrict__ cursor,
                                                 int2* __restrict__ colRow, int N) {
    int b = blockIdx.x;
    int nlo = b << BIN_SHIFT;
    int nhi = min(nlo + (1 << BIN_SHIFT), N);
    int lo = rowptr[nlo];
    int hi = rowptr[nhi];
    for (int i = lo + threadIdx.x; i < hi; i += 256) {
        int2 sd = tmpE[i];
        int p = rowptr[sd.y] + atomicAdd(&cursor[sd.y], 1);
        colRow[p] = sd;
    }
}

// ---------------- h = X @ W (register-tiled), bf16 Hout + fp32 alphas ----------------

__global__ __launch_bounds__(256) void gemm_alpha_k(const float* __restrict__ X, const float* __restrict__ W,
                                                    const float* __restrict__ a_s, const float* __restrict__ a_d,
                                                    unsigned short* __restrict__ Hout, float* __restrict__ asrc,
                                                    float* __restrict__ adst, int N) {
    __shared__ float Xt[32][68];   // [k][row], pad 68 keeps 16B alignment
    __shared__ float Wl[32][128];
    const int tid = threadIdx.x;
    const int rowBase = blockIdx.x * 64;
    const int tr = tid >> 5;   // 0..7
    const int tc = tid & 31;   // 0..31

    float acc[8][4];
#pragma unroll
    for (int i = 0; i < 8; ++i)
#pragma unroll
        for (int c = 0; c < 4; ++c) acc[i][c] = 0.f;

    for (int kc = 0; kc < 128; kc += 32) {
#pragma unroll
        for (int j = 0; j < 2; ++j) {
            int f = tid + 256 * j;       // 0..511
            int r = f >> 3;              // 0..63
            int kq = (f & 7) * 4;        // 0..28
            int gr = rowBase + r;
            float4 xv = make_float4(0.f, 0.f, 0.f, 0.f);
            if (gr < N) xv = *(const float4*)&X[(size_t)gr * 128 + kc + kq];
            Xt[kq + 0][r] = xv.x;
            Xt[kq + 1][r] = xv.y;
            Xt[kq + 2][r] = xv.z;
            Xt[kq + 3][r] = xv.w;
        }
#pragma unroll
        for (int j = 0; j < 4; ++j) {
            int f = tid + 256 * j;       // 0..1023
            int k = f >> 5;              // 0..31
            int c4 = (f & 31) * 4;       // 0..124
            *(float4*)&Wl[k][c4] = *(const float4*)&W[(size_t)(kc + k) * 128 + c4];
        }
        __syncthreads();

#pragma unroll
        for (int k = 0; k < 32; ++k) {
            float4 x0 = *(const float4*)&Xt[k][tr * 8];
            float4 x1 = *(const float4*)&Xt[k][tr * 8 + 4];
            float4 wv = *(const float4*)&Wl[k][tc * 4];
            const float xs[8] = {x0.x, x0.y, x0.z, x0.w, x1.x, x1.y, x1.z, x1.w};
#pragma unroll
            for (int i = 0; i < 8; ++i) {
                acc[i][0] = fmaf(xs[i], wv.x, acc[i][0]);
                acc[i][1] = fmaf(xs[i], wv.y, acc[i][1]);
                acc[i][2] = fmaf(xs[i], wv.z, acc[i][2]);
                acc[i][3] = fmaf(xs[i], wv.w, acc[i][3]);
            }
        }
        __syncthreads();
    }

    float4 asv = *(const float4*)&a_s[tc * 4];
    float4 adv = *(const float4*)&a_d[tc * 4];
    const int head = tc >> 3;

#pragma unroll
    for (int i = 0; i < 8; ++i) {
        float ps = acc[i][0] * asv.x + acc[i][1] * asv.y + acc[i][2] * asv.z + acc[i][3] * asv.w;
        float pd = acc[i][0] * adv.x + acc[i][1] * adv.y + acc[i][2] * adv.z + acc[i][3] * adv.w;
        ps += __shfl_down(ps, 4, 8);
        ps += __shfl_down(ps, 2, 8);
        ps += __shfl_down(ps, 1, 8);
        pd += __shfl_down(pd, 4, 8);
        pd += __shfl_down(pd, 2, 8);
        pd += __shfl_down(pd, 1, 8);
        int gr = rowBase + tr * 8 + i;
        if (gr < N) {
            uint2 pk = make_uint2(pack_bf2(acc[i][0], acc[i][1]), pack_bf2(acc[i][2], acc[i][3]));
            *(uint2*)&Hout[(size_t)gr * 128 + tc * 4] = pk;
            if ((tid & 7) == 0) {
                asrc[gr * 4 + head] = ps;
                adst[gr * 4 + head] = pd;
            }
        }
    }
}

// ---------------- edge-parallel unnormalized weights (no atomics) ----------------

__global__ __launch_bounds__(256) void wgt_k(const int2* __restrict__ colRow,
                                             const float* __restrict__ asrc, const float* __restrict__ adst,
                                             float* __restrict__ wgtA, int M) {
    int p = blockIdx.x * 256 + threadIdx.x;
    if (p >= M) return;
    int2 sd = colRow[p];
    float4 as = *(const float4*)&asrc[sd.x * 4];
    float4 ad = *(const float4*)&adst[sd.y * 4];
    float4 w;
    w.x = __expf(lrelu(as.x + ad.x));
    w.y = __expf(lrelu(as.y + ad.y));
    w.z = __expf(lrelu(as.z + ad.z));
    w.w = __expf(lrelu(as.w + ad.w));
    *(float4*)&wgtA[(size_t)p * 4] = w;
}

// ---------------- aggregation: one wave per dst node, unroll x8, bf16 h gathers ----------------

__global__ __launch_bounds__(256) void aggregate_k(const unsigned short* __restrict__ Hbuf,
                                                   const float* __restrict__ wgtA,
                                                   const int* __restrict__ rowptr,
                                                   const int2* __restrict__ colRow,
                                                   const float* __restrict__ bias,
                                                   float* __restrict__ out, int N) {
    int wave = (blockIdx.x * 256 + threadIdx.x) >> 6;
    int lane = threadIdx.x & 63;
    if (wave >= N) return;
    int n = wave;
    int c0 = lane * 2;
    int head = c0 >> 5;
    float acc0 = 0.f, acc1 = 0.f, sw = 0.f;
    int b = rowptr[n], e = rowptr[n + 1];
    int p = b;
    for (; p + 8 <= e; p += 8) {
        int s[8];
#pragma unroll
        for (int j = 0; j < 8; ++j) s[j] = colRow[p + j].x;
        float w[8];
#pragma unroll
        for (int j = 0; j < 8; ++j) w[j] = wgtA[(size_t)(p + j) * 4 + head];
        unsigned hu[8];
#pragma unroll
        for (int j = 0; j < 8; ++j) hu[j] = *(const unsigned*)&Hbuf[(size_t)s[j] * 128 + c0];
#pragma unroll
        for (int j = 0; j < 8; ++j) {
            float h0 = __uint_as_float(hu[j] << 16);
            float h1 = __uint_as_float(hu[j] & 0xffff0000u);
            sw += w[j];
            acc0 = fmaf(w[j], h0, acc0);
            acc1 = fmaf(w[j], h1, acc1);
        }
    }
    for (; p + 2 <= e; p += 2) {
        int s0 = colRow[p].x, s1 = colRow[p + 1].x;
        float w0 = wgtA[(size_t)p * 4 + head];
        float w1 = wgtA[(size_t)(p + 1) * 4 + head];
        unsigned u0 = *(const unsigned*)&Hbuf[(size_t)s0 * 128 + c0];
        unsigned u1 = *(const unsigned*)&Hbuf[(size_t)s1 * 128 + c0];
        sw += w0 + w1;
        acc0 = fmaf(w0, __uint_as_float(u0 << 16), acc0);
        acc1 = fmaf(w0, __uint_as_float(u0 & 0xffff0000u), acc1);
        acc0 = fmaf(w1, __uint_as_float(u1 << 16), acc0);
        acc1 = fmaf(w1, __uint_as_float(u1 & 0xffff0000u), acc1);
    }
    for (; p < e; ++p) {
        int s = colRow[p].x;
        float w = wgtA[(size_t)p * 4 + head];
        unsigned u = *(const unsigned*)&Hbuf[(size_t)s * 128 + c0];
        sw += w;
        acc0 = fmaf(w, __uint_as_float(u << 16), acc0);
        acc1 = fmaf(w, __uint_as_float(u & 0xffff0000u), acc1);
    }
    float inv_dh = 1.f / sw;
    float o0 = fmaxf(acc0 * inv_dh + bias[c0], 0.f);
    float o1 = fmaxf(acc1 * inv_dh + bias[c0 + 1], 0.f);
    *(float2*)&out[(size_t)n * 128 + c0] = make_float2(o0, o1);
}

// ---------------- launch ----------------

extern "C" void kernel_launch(void* const* d_in, const int* in_sizes, int n_in,
                              void* d_out, int out_size, void* d_ws, size_t ws_size,
                              hipStream_t stream) {
    const float* X   = (const float*)d_in[0];
    const int*   EI  = (const int*)d_in[1];
    const float* W1  = (const float*)d_in[2];
    const float* as1 = (const float*)d_in[3];
    const float* ad1 = (const float*)d_in[4];
    const float* b1  = (const float*)d_in[5];
    const float* W2  = (const float*)d_in[6];
    const float* as2 = (const float*)d_in[7];
    const float* ad2 = (const float*)d_in[8];
    const float* b2  = (const float*)d_in[9];

    const int N = in_sizes[0] / 128;
    const int E = in_sizes[1] / 2;
    const int M = E + N;
    const int K = (N + (1 << BIN_SHIFT) - 1) >> BIN_SHIFT;   // <= 256 for N <= 131072
    const int* srcI = EI;
    const int* dstI = EI + E;

    char* w = (char*)d_ws;
    auto alloc = [&](size_t bytes) {
        char* p = w;
        w += (bytes + 255) & ~(size_t)255;
        return p;
    };
    unsigned short* Hbuf = (unsigned short*)alloc((size_t)N * 128 * 2);  // bf16
    float* wgtA   = (float*)alloc((size_t)M * 4 * 4);
    float* asrc   = (float*)alloc((size_t)N * 4 * 4);
    float* adst   = (float*)alloc((size_t)N * 4 * 4);
    int*   cnt    = (int*)alloc((size_t)N * 4);      // cnt+cursor contiguous: one memset
    int*   cursor = (int*)alloc((size_t)N * 4);
    int*   rowptr = (int*)alloc((size_t)(N + 1) * 4);
    int2*  colRow = (int2*)alloc((size_t)M * 8);
    int2*  tmpE   = (int2*)alloc((size_t)M * 8);
    int*   bcur   = (int*)alloc(256 * 4);
    int*   bsum   = (int*)alloc(1024 * 4);

    hipMemsetAsync(cnt, 0, (char*)(cursor + N) - (char*)cnt, stream);

    // CSR build (shared by both layers)
    count_deg_k<<<(E / 4 + 256) / 256, 256, 0, stream>>>(dstI, E, N, cnt);
    int nb1 = (N + 1023) / 1024;
    scan1_k<<<nb1, 256, 0, stream>>>(cnt, N, rowptr, bsum);
    scan2_k<<<1, 256, 0, stream>>>(bsum, nb1);
    scan3_k<<<(N + 1 + 255) / 256, 256, 0, stream>>>(rowptr, bsum, N, M);
    init_bcur_k<<<(K + 255) / 256, 256, 0, stream>>>(rowptr, bcur, K);
    bin_k<<<(M + 4095) / 4096, 256, 0, stream>>>(srcI, dstI, E, N, K, bcur, tmpE);
    scatter_k<<<K, 256, 0, stream>>>(tmpE, rowptr, cursor, colRow, N);

    float* out = (float*)d_out;

    // layer 1 (activation staged in d_out, fp32)
    gemm_alpha_k<<<(N + 63) / 64, 256, 0, stream>>>(X, W1, as1, ad1, Hbuf, asrc, adst, N);
    wgt_k<<<(M + 255) / 256, 256, 0, stream>>>(colRow, asrc, adst, wgtA, M);
    aggregate_k<<<((size_t)N * 64 + 255) / 256, 256, 0, stream>>>(Hbuf, wgtA, rowptr, colRow, b1, out, N);
    // layer 2
    gemm_alpha_k<<<(N + 63) / 64, 256, 0, stream>>>(out, W2, as2, ad2, Hbuf, asrc, adst, N);
    wgt_k<<<(M + 255) / 256, 256, 0, stream>>>(colRow, asrc, adst, wgtA, M);
    aggregate_k<<<((size_t)N * 64 + 255) / 256, 256, 0, stream>>>(Hbuf, wgtA, rowptr, colRow, b2, out, N);
}